// Round 1
// baseline (889.692 us; speedup 1.0000x reference)
//
#include <hip/hip_runtime.h>

#define NROWS 65536   // 64*32*32
#define D     256
#define K     2048
#define BM    32
#define NBLK  (NROWS / BM)   // 2048

// ws layout (floats):
//   enorm  [0, K)
//   Etg    [K, K + K*D)          transposed embeddings, Etg[k][d]
//   partial[K + K*D, + NBLK)
// total ~2.02 MB

// --- Kernel 1: per-code squared norms + transposed copy of embeddings ---
__global__ __launch_bounds__(256) void vq_prep(const float* __restrict__ E,
                                               float* __restrict__ enorm,
                                               float* __restrict__ Etg) {
  const int k = blockIdx.x;      // one block per code
  const int d = threadIdx.x;     // 256 threads over depth
  float v = E[(size_t)d * K + k];
  Etg[(size_t)k * D + d] = v;
  float s = v * v;
  #pragma unroll
  for (int off = 32; off; off >>= 1) s += __shfl_xor(s, off);
  __shared__ float wsum[4];
  if ((threadIdx.x & 63) == 0) wsum[threadIdx.x >> 6] = s;
  __syncthreads();
  if (threadIdx.x == 0) enorm[k] = (wsum[0] + wsum[1]) + (wsum[2] + wsum[3]);
}

// --- Kernel 2: fused distance-GEMM + argmin + gather + loss partials ---
__global__ __launch_bounds__(256) void vq_main(const float* __restrict__ x,
                                               const float* __restrict__ E,
                                               const float* __restrict__ enorm,
                                               const float* __restrict__ Etg,
                                               float* __restrict__ out,
                                               float* __restrict__ partial) {
  __shared__ float Xt[D][BM];      // transposed x tile, 32 KB
  __shared__ float fpart[8][BM];   // row-norm partials
  __shared__ float fnorm[BM];
  __shared__ int   idx_sh[BM];
  __shared__ float lpart[4];

  const int tid  = threadIdx.x;
  const int blk  = blockIdx.x;
  const int lane = tid & 63;
  const int wv   = tid >> 6;       // wave 0..3
  const int w8   = wv * 8;         // this wave's first row (8 rows per wave)

  const float* xblk = x + (size_t)blk * BM * D;

  // ---- stage X transposed into LDS; accumulate row-norm partials ----
  {
    const int r  = tid & 31;       // row
    const int dq = tid >> 5;       // 0..7
    float fs = 0.f;
    #pragma unroll
    for (int i = 0; i < 8; ++i) {
      const int d0 = dq * 4 + i * 32;
      float4 v = *reinterpret_cast<const float4*>(xblk + r * D + d0);
      Xt[d0 + 0][r] = v.x; Xt[d0 + 1][r] = v.y;
      Xt[d0 + 2][r] = v.z; Xt[d0 + 3][r] = v.w;
      fs += v.x * v.x + v.y * v.y + v.z * v.z + v.w * v.w;
    }
    fpart[dq][r] = fs;
  }
  __syncthreads();
  if (tid < BM) {
    float f = 0.f;
    #pragma unroll
    for (int q = 0; q < 8; ++q) f += fpart[q][tid];
    fnorm[tid] = f;
  }
  __syncthreads();

  float frow[8];
  #pragma unroll
  for (int i = 0; i < 8; ++i) frow[i] = fnorm[w8 + i];

  float bestv[8];
  int   besti[8];
  #pragma unroll
  for (int i = 0; i < 8; ++i) { bestv[i] = 3.4e38f; besti[i] = 0x7fffffff; }

  // ---- sweep K in tiles of 256 codes; each lane owns 4 codes ----
  for (int t8 = 0; t8 < K / 256; ++t8) {
    const int cb = t8 * 256 + lane * 4;
    const float* Ecol = E + cb;
    float acc[8][4];
    #pragma unroll
    for (int i = 0; i < 8; ++i)
      #pragma unroll
      for (int j = 0; j < 4; ++j) acc[i][j] = 0.f;

    #pragma unroll 4
    for (int d = 0; d < D; ++d) {
      float4 bv = *reinterpret_cast<const float4*>(Ecol + (size_t)d * K);
      float4 a0 = *reinterpret_cast<const float4*>(&Xt[d][w8]);      // wave-uniform broadcast
      float4 a1 = *reinterpret_cast<const float4*>(&Xt[d][w8 + 4]);
      const float a[8] = {a0.x, a0.y, a0.z, a0.w, a1.x, a1.y, a1.z, a1.w};
      const float b[4] = {bv.x, bv.y, bv.z, bv.w};
      #pragma unroll
      for (int i = 0; i < 8; ++i)
        #pragma unroll
        for (int j = 0; j < 4; ++j)
          acc[i][j] = fmaf(a[i], b[j], acc[i][j]);
    }

    float4 en = *reinterpret_cast<const float4*>(enorm + cb);
    const float enf[4] = {en.x, en.y, en.z, en.w};
    #pragma unroll
    for (int i = 0; i < 8; ++i) {
      #pragma unroll
      for (int j = 0; j < 4; ++j) {
        const float dist = (frow[i] + enf[j]) - 2.0f * acc[i][j];
        if (dist < bestv[i]) { bestv[i] = dist; besti[i] = cb + j; }
      }
    }
  }

  // ---- in-wave argmin reduction (all 64 lanes share the wave's 8 rows) ----
  #pragma unroll
  for (int off = 32; off; off >>= 1) {
    #pragma unroll
    for (int i = 0; i < 8; ++i) {
      const float ov = __shfl_xor(bestv[i], off);
      const int   oi = __shfl_xor(besti[i], off);
      if (ov < bestv[i] || (ov == bestv[i] && oi < besti[i])) {
        bestv[i] = ov; besti[i] = oi;
      }
    }
  }
  if (lane == 0) {
    #pragma unroll
    for (int i = 0; i < 8; ++i) idx_sh[w8 + i] = besti[i];
  }
  __syncthreads();

  // ---- epilogue: gather quantised rows, write out, loss partial ----
  float lsum = 0.f;
  float* outb = out + (size_t)blk * BM * D;
  for (int r = 0; r < BM; ++r) {
    const int kidx = idx_sh[r];
    const float q  = Etg[(size_t)kidx * D + tid];  // coalesced, L2-resident
    const float xv = xblk[r * D + tid];            // coalesced, L2-hot
    const float df = q - xv;
    lsum += df * df;
    outb[r * D + tid] = q;
  }
  #pragma unroll
  for (int off = 32; off; off >>= 1) lsum += __shfl_xor(lsum, off);
  if (lane == 0) lpart[wv] = lsum;
  __syncthreads();
  if (tid == 0) partial[blk] = (lpart[0] + lpart[1]) + (lpart[2] + lpart[3]);
}

// --- Kernel 3: deterministic final loss reduction ---
__global__ __launch_bounds__(256) void vq_final(const float* __restrict__ partial,
                                                float* __restrict__ loss_out) {
  double s = 0.0;
  for (int i = threadIdx.x; i < NBLK; i += 256) s += (double)partial[i];
  #pragma unroll
  for (int off = 32; off; off >>= 1) s += __shfl_xor(s, off);
  __shared__ double sh[4];
  if ((threadIdx.x & 63) == 0) sh[threadIdx.x >> 6] = s;
  __syncthreads();
  if (threadIdx.x == 0) {
    const double mean = (sh[0] + sh[1] + sh[2] + sh[3]) / 16777216.0;
    loss_out[0] = (float)(0.25 * mean - mean);   // beta*commit - codebook
  }
}

extern "C" void kernel_launch(void* const* d_in, const int* in_sizes, int n_in,
                              void* d_out, int out_size, void* d_ws, size_t ws_size,
                              hipStream_t stream) {
  const float* x = (const float*)d_in[0];     // [65536, 256]
  const float* E = (const float*)d_in[1];     // [256, 2048]
  float* out = (float*)d_out;                 // 16777216 + 1
  float* ws  = (float*)d_ws;

  float* enorm   = ws;                        // K floats
  float* Etg     = ws + K;                    // K*D floats
  float* partial = Etg + (size_t)K * D;       // NBLK floats

  vq_prep <<<K,    256, 0, stream>>>(E, enorm, Etg);
  vq_main <<<NBLK, 256, 0, stream>>>(x, E, enorm, Etg, out, partial);
  vq_final<<<1,    256, 0, stream>>>(partial, out + (size_t)NROWS * D);
}

// Round 2
// 354.974 us; speedup vs baseline: 2.5064x; 2.5064x over previous
//
#include <hip/hip_runtime.h>

typedef __attribute__((ext_vector_type(8))) short bf16x8;
typedef __attribute__((ext_vector_type(4))) float f32x4;
typedef __attribute__((ext_vector_type(8))) unsigned short u16x8;

#define NROWS 65536
#define DDIM  256
#define KCODE 2048
#define BM    128
#define BN    256
#define NCT   (KCODE / BN)    // 8
#define NKB   12              // virtual K = 768 = hi*hi | lo*hi | hi*lo
#define NBLK  (NROWS / BM)    // 512

__device__ __forceinline__ unsigned short f2bf_rne(float f) {
  unsigned int u = __builtin_bit_cast(unsigned int, f);
  unsigned int r = (u + 0x7fffu + ((u >> 16) & 1u)) >> 16;
  return (unsigned short)r;
}
__device__ __forceinline__ float bf2f(unsigned short h) {
  unsigned int u = ((unsigned int)h) << 16;
  return __builtin_bit_cast(float, u);
}

typedef const unsigned int __attribute__((address_space(1)))* gp1_t;
typedef unsigned int __attribute__((address_space(3)))* lp3_t;
__device__ __forceinline__ void gload_lds16(const void* g, void* l) {
  __builtin_amdgcn_global_load_lds((gp1_t)g, (lp3_t)l, 16, 0, 0);
}

// --- prep A: x -> [hi(256)|lo(256)] bf16 per row (written into d_out overlay) + ||x_row||^2 ---
__global__ __launch_bounds__(256) void prep_A(const float* __restrict__ x,
                                              unsigned short* __restrict__ Ap,
                                              float* __restrict__ frow) {
  const int t   = threadIdx.x;
  const int row = blockIdx.x * 8 + (t >> 5);
  const int d0  = (t & 31) * 8;
  const float* xr = x + (size_t)row * DDIM + d0;
  float4 v0 = *reinterpret_cast<const float4*>(xr);
  float4 v1 = *reinterpret_cast<const float4*>(xr + 4);
  float vv[8] = {v0.x, v0.y, v0.z, v0.w, v1.x, v1.y, v1.z, v1.w};
  u16x8 hi, lo;
  float ss = 0.f;
  #pragma unroll
  for (int i = 0; i < 8; ++i) {
    ss += vv[i] * vv[i];
    unsigned short h = f2bf_rne(vv[i]);
    hi[i] = (unsigned short)h;
    lo[i] = f2bf_rne(vv[i] - bf2f(h));
  }
  char* rowp = (char*)Ap + (size_t)row * 1024;
  *reinterpret_cast<u16x8*>(rowp + d0 * 2)       = hi;
  *reinterpret_cast<u16x8*>(rowp + 512 + d0 * 2) = lo;
  #pragma unroll
  for (int off = 16; off; off >>= 1) ss += __shfl_xor(ss, off);
  if ((t & 31) == 0) frow[row] = ss;
}

// --- prep B: E[d][k] -> Bp[k][768]=[hi|hi|lo] bf16 (k-major), enorm, Etg[k][d] fp32 ---
__global__ __launch_bounds__(256) void prep_B(const float* __restrict__ E,
                                              unsigned short* __restrict__ Bp,
                                              float* __restrict__ enorm,
                                              float* __restrict__ Etg) {
  const int k0 = blockIdx.x;
  const int d  = threadIdx.x;
  float v = E[(size_t)d * KCODE + k0];
  Etg[(size_t)k0 * DDIM + d] = v;
  unsigned short h = f2bf_rne(v);
  unsigned short l = f2bf_rne(v - bf2f(h));
  unsigned short* col = Bp + (size_t)k0 * 768;
  col[d] = h; col[256 + d] = h; col[512 + d] = l;
  float s = v * v;
  #pragma unroll
  for (int off = 32; off; off >>= 1) s += __shfl_xor(s, off);
  __shared__ float wsum[4];
  if ((threadIdx.x & 63) == 0) wsum[threadIdx.x >> 6] = s;
  __syncthreads();
  if (threadIdx.x == 0) enorm[k0] = (wsum[0] + wsum[1]) + (wsum[2] + wsum[3]);
}

// --- main: MFMA distance GEMM + fused argmin + gather + loss partials ---
__global__ __launch_bounds__(512) void vq_mfma(
    const float* __restrict__ x,
    const unsigned short* Ap,            // aliases out (overlay) - no restrict
    const unsigned short* __restrict__ Bp,
    const float* __restrict__ enorm,
    const float* __restrict__ frow,
    const float* __restrict__ Etg,
    float* out,                          // aliases Ap - no restrict
    float* __restrict__ partial)
{
  __shared__ __align__(16) char lds[49152];   // A tile 16KB | B tile 32KB
  __shared__ float redv[BM][4];
  __shared__ int   redi[BM][4];
  __shared__ int   idx_sh[BM];
  __shared__ float lpart[8];

  const int tid = threadIdx.x;
  const int w   = tid >> 6;
  const int l   = tid & 63;
  const int l15 = l & 15;
  const int lg  = l >> 4;
  const int wr  = w >> 2;      // 0..1 : row half
  const int wc  = w & 3;       // 0..3 : col quarter
  const int rb  = blockIdx.x * BM;

  int aOff[4], aSwz[4];
  #pragma unroll
  for (int fr = 0; fr < 4; ++fr) {
    const int rl = wr * 64 + fr * 16 + l15;
    aOff[fr] = rl * 128; aSwz[fr] = (rl & 7) << 4;
  }
  int bOff[4], bSwz[4];
  #pragma unroll
  for (int fc = 0; fc < 4; ++fc) {
    const int cl = wc * 64 + fc * 16 + l15;
    bOff[fc] = 16384 + cl * 128; bSwz[fc] = (cl & 7) << 4;
  }

  float frw[16];
  #pragma unroll
  for (int fr = 0; fr < 4; ++fr)
    #pragma unroll
    for (int rg = 0; rg < 4; ++rg)
      frw[fr * 4 + rg] = frow[rb + wr * 64 + fr * 16 + lg * 4 + rg];

  float bestv[16]; int besti[16];
  #pragma unroll
  for (int i = 0; i < 16; ++i) { bestv[i] = 3.4e38f; besti[i] = 0; }

  const char* ApB = (const char*)Ap;
  const char* BpB = (const char*)Bp;
  const int chunk = (tid & 7) * 16;
  const int rl0   = tid >> 3;          // 0..63

  for (int ct = 0; ct < NCT; ++ct) {
    float en[4];
    #pragma unroll
    for (int fc = 0; fc < 4; ++fc) en[fc] = enorm[ct * BN + wc * 64 + fc * 16 + l15];

    f32x4 acc[4][4];
    #pragma unroll
    for (int fr = 0; fr < 4; ++fr)
      #pragma unroll
      for (int fc = 0; fc < 4; ++fc) acc[fr][fc] = (f32x4){0.f, 0.f, 0.f, 0.f};

    for (int kb = 0; kb < NKB; ++kb) {
      __syncthreads();                 // LDS safe to overwrite
      const int aColB = (kb < 8 ? kb : kb - 8) * 128;   // [hi|lo] then hi again
      #pragma unroll
      for (int q = 0; q < 2; ++q) {    // A: 128 rows x 128B
        const int rl = q * 64 + rl0;
        const char* src = ApB + (size_t)(rb + rl) * 1024 + aColB + (chunk ^ ((rl & 7) << 4));
        gload_lds16(src, lds + q * 8192 + w * 1024);
      }
      #pragma unroll
      for (int q = 0; q < 4; ++q) {    // B: 256 cols x 128B
        const int cl = q * 64 + rl0;
        const char* src = BpB + (size_t)(ct * BN + cl) * 1536 + kb * 128 + (chunk ^ ((cl & 7) << 4));
        gload_lds16(src, lds + 16384 + q * 8192 + w * 1024);
      }
      __syncthreads();                 // drains vmcnt, data ready

      #pragma unroll
      for (int ks = 0; ks < 2; ++ks) {
        const int ko = ks * 64 + lg * 16;
        bf16x8 aF[4], bF[4];
        #pragma unroll
        for (int fr = 0; fr < 4; ++fr)
          aF[fr] = *reinterpret_cast<const bf16x8*>(lds + aOff[fr] + (ko ^ aSwz[fr]));
        #pragma unroll
        for (int fc = 0; fc < 4; ++fc)
          bF[fc] = *reinterpret_cast<const bf16x8*>(lds + bOff[fc] + (ko ^ bSwz[fc]));
        #pragma unroll
        for (int fr = 0; fr < 4; ++fr)
          #pragma unroll
          for (int fc = 0; fc < 4; ++fc)
            acc[fr][fc] = __builtin_amdgcn_mfma_f32_16x16x32_bf16(aF[fr], bF[fc], acc[fr][fc], 0, 0, 0);
      }
    }

    // dist = (||f||^2 + ||e||^2) - 2*sim ; running argmin (codes ascending -> strict <)
    #pragma unroll
    for (int fr = 0; fr < 4; ++fr)
      #pragma unroll
      for (int fc = 0; fc < 4; ++fc) {
        const int code = ct * BN + wc * 64 + fc * 16 + l15;
        #pragma unroll
        for (int rg = 0; rg < 4; ++rg) {
          const float dist = (frw[fr * 4 + rg] + en[fc]) - 2.0f * acc[fr][fc][rg];
          if (dist < bestv[fr * 4 + rg]) { bestv[fr * 4 + rg] = dist; besti[fr * 4 + rg] = code; }
        }
      }
  }

  // reduce across the 16 lanes sharing each row (xor over low 4 lane bits)
  #pragma unroll
  for (int off = 1; off < 16; off <<= 1)
    #pragma unroll
    for (int i = 0; i < 16; ++i) {
      const float ov = __shfl_xor(bestv[i], off);
      const int   oi = __shfl_xor(besti[i], off);
      if (ov < bestv[i] || (ov == bestv[i] && oi < besti[i])) { bestv[i] = ov; besti[i] = oi; }
    }
  if (l15 == 0) {
    #pragma unroll
    for (int fr = 0; fr < 4; ++fr)
      #pragma unroll
      for (int rg = 0; rg < 4; ++rg) {
        const int r = wr * 64 + fr * 16 + lg * 4 + rg;
        redv[r][wc] = bestv[fr * 4 + rg];
        redi[r][wc] = besti[fr * 4 + rg];
      }
  }
  __syncthreads();
  if (tid < BM) {
    float bv = redv[tid][0]; int bi = redi[tid][0];
    #pragma unroll
    for (int c = 1; c < 4; ++c) {
      const float v2 = redv[tid][c]; const int i2 = redi[tid][c];
      if (v2 < bv || (v2 == bv && i2 < bi)) { bv = v2; bi = i2; }
    }
    idx_sh[tid] = bi;
  }
  __syncthreads();

  // gather + out write (overwrites this block's A' slab - all reads done) + loss
  float lsum = 0.f;
  const int d    = tid & 255;
  const int half = tid >> 8;
  for (int rr = 0; rr < BM / 2; ++rr) {
    const int rl = rr * 2 + half;
    const int kq = idx_sh[rl];
    const float q  = Etg[(size_t)kq * DDIM + d];
    const float xv = x[(size_t)(rb + rl) * DDIM + d];
    out[(size_t)(rb + rl) * DDIM + d] = q;
    const float df = q - xv;
    lsum += df * df;
  }
  #pragma unroll
  for (int off = 32; off; off >>= 1) lsum += __shfl_xor(lsum, off);
  if (l == 0) lpart[w] = lsum;
  __syncthreads();
  if (tid == 0) {
    float s = 0.f;
    #pragma unroll
    for (int i = 0; i < 8; ++i) s += lpart[i];
    partial[blockIdx.x] = s;
  }
}

// --- final deterministic loss reduction ---
__global__ __launch_bounds__(256) void vq_final(const float* __restrict__ partial,
                                                float* __restrict__ loss_out) {
  double s = 0.0;
  for (int i = threadIdx.x; i < NBLK; i += 256) s += (double)partial[i];
  #pragma unroll
  for (int off = 32; off; off >>= 1) s += __shfl_xor(s, off);
  __shared__ double sh[4];
  if ((threadIdx.x & 63) == 0) sh[threadIdx.x >> 6] = s;
  __syncthreads();
  if (threadIdx.x == 0) {
    const double mean = (sh[0] + sh[1] + sh[2] + sh[3]) / 16777216.0;
    loss_out[0] = (float)(0.25 * mean - mean);
  }
}

extern "C" void kernel_launch(void* const* d_in, const int* in_sizes, int n_in,
                              void* d_out, int out_size, void* d_ws, size_t ws_size,
                              hipStream_t stream) {
  const float* x = (const float*)d_in[0];   // [65536, 256]
  const float* E = (const float*)d_in[1];   // [256, 2048]
  float* out = (float*)d_out;
  float* ws  = (float*)d_ws;

  float* enorm   = ws;                          // 2048
  float* frow    = ws + 2048;                   // 65536
  float* partial = ws + 2048 + 65536;           // 512
  float* Etg     = ws + 68096;                  // 2048*256
  unsigned short* Bp = (unsigned short*)(ws + 68096 + 524288);  // 2048*768 bf16

  unsigned short* Ap = (unsigned short*)d_out;  // A' overlay on out (same 1024B row stride)

  prep_A <<<NROWS / 8, 256, 0, stream>>>(x, Ap, frow);
  prep_B <<<KCODE,     256, 0, stream>>>(E, Bp, enorm, Etg);
  vq_mfma<<<NBLK,      512, 0, stream>>>(x, Ap, Bp, enorm, frow, Etg, out, partial);
  vq_final<<<1,        256, 0, stream>>>(partial, out + (size_t)NROWS * DDIM);
}

// Round 3
// 242.817 us; speedup vs baseline: 3.6640x; 1.4619x over previous
//
#include <hip/hip_runtime.h>

typedef __attribute__((ext_vector_type(8))) short bf16x8;
typedef __attribute__((ext_vector_type(4))) float f32x4;
typedef __attribute__((ext_vector_type(8))) unsigned short u16x8;
typedef unsigned long long u64t;
typedef unsigned int u32t;

#define NROWS 65536
#define DDIM  256
#define KCODE 2048

__device__ __forceinline__ unsigned short f2bf_rne(float f) {
  unsigned int u = __builtin_bit_cast(unsigned int, f);
  unsigned int r = (u + 0x7fffu + ((u >> 16) & 1u)) >> 16;
  return (unsigned short)r;
}
__device__ __forceinline__ float bf2f(unsigned short h) {
  unsigned int u = ((unsigned int)h) << 16;
  return __builtin_bit_cast(float, u);
}

typedef const unsigned int __attribute__((address_space(1)))* gp1_t;
typedef unsigned int __attribute__((address_space(3)))* lp3_t;
__device__ __forceinline__ void gload_lds16(const void* g, void* l) {
  __builtin_amdgcn_global_load_lds((gp1_t)g, (lp3_t)l, 16, 0, 0);
}

__device__ __forceinline__ u64t shfl_xor_u64(u64t v, int off) {
  u32t lo = (u32t)v, hi = (u32t)(v >> 32);
  lo = __shfl_xor(lo, off);
  hi = __shfl_xor(hi, off);
  return ((u64t)hi << 32) | lo;
}

// --- prep A: x -> [hi(256)|lo(256)] bf16 per row (overlay on d_out) + ||x||^2 + key init ---
__global__ __launch_bounds__(256) void prep_A(const float* __restrict__ x,
                                              unsigned short* __restrict__ Ap,
                                              float* __restrict__ frow,
                                              u64t* __restrict__ keyArr) {
  const int t   = threadIdx.x;
  const int row = blockIdx.x * 8 + (t >> 5);
  const int d0  = (t & 31) * 8;
  const float* xr = x + (size_t)row * DDIM + d0;
  float4 v0 = *reinterpret_cast<const float4*>(xr);
  float4 v1 = *reinterpret_cast<const float4*>(xr + 4);
  float vv[8] = {v0.x, v0.y, v0.z, v0.w, v1.x, v1.y, v1.z, v1.w};
  u16x8 hi, lo;
  float ss = 0.f;
  #pragma unroll
  for (int i = 0; i < 8; ++i) {
    ss += vv[i] * vv[i];
    unsigned short h = f2bf_rne(vv[i]);
    hi[i] = h;
    lo[i] = f2bf_rne(vv[i] - bf2f(h));
  }
  char* rowp = (char*)Ap + (size_t)row * 1024;
  *reinterpret_cast<u16x8*>(rowp + d0 * 2)       = hi;
  *reinterpret_cast<u16x8*>(rowp + 512 + d0 * 2) = lo;
  #pragma unroll
  for (int off = 16; off; off >>= 1) ss += __shfl_xor(ss, off);
  if ((t & 31) == 0) { frow[row] = ss; keyArr[row] = ~0ull; }
}

// --- prep B: E[d][k] -> Bp[k][768]=[hi|hi|lo] bf16 k-major; enorm; Etg[k][d] fp32 ---
__global__ __launch_bounds__(256) void prep_B(const float* __restrict__ E,
                                              unsigned short* __restrict__ Bp,
                                              float* __restrict__ enorm,
                                              float* __restrict__ Etg) {
  const int k0 = blockIdx.x;
  const int d  = threadIdx.x;
  float v = E[(size_t)d * KCODE + k0];
  Etg[(size_t)k0 * DDIM + d] = v;
  unsigned short h = f2bf_rne(v);
  unsigned short l = f2bf_rne(v - bf2f(h));
  unsigned short* col = Bp + (size_t)k0 * 768;
  col[d] = h; col[256 + d] = h; col[512 + d] = l;
  float s = v * v;
  #pragma unroll
  for (int off = 32; off; off >>= 1) s += __shfl_xor(s, off);
  __shared__ float wsum[4];
  if ((threadIdx.x & 63) == 0) wsum[threadIdx.x >> 6] = s;
  __syncthreads();
  if (threadIdx.x == 0) enorm[k0] = (wsum[0] + wsum[1]) + (wsum[2] + wsum[3]);
}

// --- main: transposed distance GEMM (codes = M), dbuf + counted vmcnt, argmin -> atomicMin ---
__global__ __launch_bounds__(512, 2) void vq_nn(
    const unsigned short* __restrict__ Ap,   // x packed  [row][hi|lo]   1024 B/row
    const unsigned short* __restrict__ Bp,   // codes     [k][hi|hi|lo]  1536 B/code
    const float* __restrict__ enorm,
    const float* __restrict__ frow,
    u64t* __restrict__ keyArr)
{
  extern __shared__ __align__(16) char lds[];   // 2 x { codes 32K | x 32K } = 128 KB

  const int tid = threadIdx.x;
  const int w   = tid >> 6;
  const int l   = tid & 63;
  const int l15 = l & 15;
  const int lg  = l >> 4;
  const int wr  = w >> 2;      // code half (0..1)
  const int wc  = w & 3;       // x-col quarter (0..3)
  const int cb  = blockIdx.x >> 8;    // code block 0..7
  const int nb  = blockIdx.x & 255;   // x-row block 0..255

  // staging mapping: thread -> (row_local = tid>>3 + q*64, chunk = (tid&7)*16)
  const int rl0   = tid >> 3;
  const int chunk = (tid & 7) * 16;
  const int srcC  = chunk ^ ((rl0 & 7) << 4);   // pre-swizzled source byte
  const char* BpB = (const char*)Bp + (size_t)cb * 256 * 1536;
  const char* ApB = (const char*)Ap + (size_t)nb * 256 * 1024;

  auto STAGE = [&](int kb, int bsel) {
    char* dstb = lds + bsel * 65536 + w * 1024;          // wave-uniform base
    const int xc = (kb < 8) ? kb : kb - 8;               // x virtual-K: [hi|lo|hi]
    #pragma unroll
    for (int q = 0; q < 4; ++q)                          // codes: 256 x 128 B
      gload_lds16(BpB + (size_t)(q * 64 + rl0) * 1536 + kb * 128 + srcC, dstb + q * 8192);
    #pragma unroll
    for (int q = 0; q < 4; ++q)                          // x: 256 x 128 B
      gload_lds16(ApB + (size_t)(q * 64 + rl0) * 1024 + xc * 128 + srcC, dstb + 32768 + q * 8192);
  };

  // ds_read addressing (XOR swizzle: row&7 == l15&7 since prefixes are mult. of 8)
  const int swz = (l15 & 7) << 4;
  int aOff[8];
  #pragma unroll
  for (int fr = 0; fr < 8; ++fr) aOff[fr] = (wr * 128 + fr * 16 + l15) * 128;
  int bOff[4];
  #pragma unroll
  for (int fc = 0; fc < 4; ++fc) bOff[fc] = 32768 + (wc * 64 + fc * 16 + l15) * 128;

  f32x4 acc[8][4];
  #pragma unroll
  for (int fr = 0; fr < 8; ++fr)
    #pragma unroll
    for (int fc = 0; fc < 4; ++fc) acc[fr][fc] = (f32x4){0.f, 0.f, 0.f, 0.f};

  STAGE(0, 0);
  for (int kb = 0; kb < 12; ++kb) {
    if (kb < 11) {
      STAGE(kb + 1, (kb + 1) & 1);                        // 8 loads in flight on top
      asm volatile("s_waitcnt vmcnt(8)" ::: "memory");    // previous stage complete
    } else {
      asm volatile("s_waitcnt vmcnt(0)" ::: "memory");
    }
    __builtin_amdgcn_s_barrier();                         // buf[kb&1] published

    const char* lb = lds + (kb & 1) * 65536;
    #pragma unroll
    for (int ks = 0; ks < 2; ++ks) {
      const int koX = (ks * 64 + lg * 16) ^ swz;
      bf16x8 aF[8], bF[4];
      #pragma unroll
      for (int fc = 0; fc < 4; ++fc)
        bF[fc] = *reinterpret_cast<const bf16x8*>(lb + bOff[fc] + koX);
      #pragma unroll
      for (int fr = 0; fr < 8; ++fr)
        aF[fr] = *reinterpret_cast<const bf16x8*>(lb + aOff[fr] + koX);
      #pragma unroll
      for (int fr = 0; fr < 8; ++fr)
        #pragma unroll
        for (int fc = 0; fc < 4; ++fc)
          acc[fr][fc] = __builtin_amdgcn_mfma_f32_16x16x32_bf16(aF[fr], bF[fc], acc[fr][fc], 0, 0, 0);
    }

    if (kb < 11) __builtin_amdgcn_s_barrier();            // all reads of buf[kb&1] done
  }

  // ---- epilogue: dist -> packed u64 key -> fold -> atomicMin per x-row ----
  // C layout: row(code_l) = wr*128 + fr*16 + lg*4 + rg ; col(x_l) = wc*64 + fc*16 + l15
  float fcol[4];
  #pragma unroll
  for (int fc = 0; fc < 4; ++fc)
    fcol[fc] = frow[nb * 256 + wc * 64 + fc * 16 + l15];

  u64t bk[4] = {~0ull, ~0ull, ~0ull, ~0ull};
  #pragma unroll
  for (int fr = 0; fr < 8; ++fr) {
    const int cbase = cb * 256 + wr * 128 + fr * 16 + lg * 4;
    float4 en4 = *reinterpret_cast<const float4*>(enorm + cbase);
    const float en[4] = {en4.x, en4.y, en4.z, en4.w};
    #pragma unroll
    for (int fc = 0; fc < 4; ++fc)
      #pragma unroll
      for (int rg = 0; rg < 4; ++rg) {
        const float dist = (fcol[fc] + en[rg]) - 2.0f * acc[fr][fc][rg];
        const u64t key = ((u64t)__builtin_bit_cast(u32t, dist) << 32) | (u32t)(cbase + rg);
        if (key < bk[fc]) bk[fc] = key;
      }
  }
  #pragma unroll
  for (int off = 16; off <= 32; off <<= 1)
    #pragma unroll
    for (int fc = 0; fc < 4; ++fc) {
      const u64t o = shfl_xor_u64(bk[fc], off);
      if (o < bk[fc]) bk[fc] = o;
    }
  if (lg == 0) {
    #pragma unroll
    for (int fc = 0; fc < 4; ++fc)
      atomicMin(&keyArr[nb * 256 + wc * 64 + fc * 16 + l15], bk[fc]);
  }
}

// --- gather: key -> code -> out write + loss partial ---
__global__ __launch_bounds__(256) void vq_gather(const u64t* __restrict__ keyArr,
                                                 const float* __restrict__ Etg,
                                                 const float* __restrict__ x,
                                                 float* __restrict__ out,
                                                 float* __restrict__ partial) {
  __shared__ int codes[128];
  __shared__ float lpart[4];
  const int t  = threadIdx.x;
  const int r0 = blockIdx.x * 128;
  if (t < 128) codes[t] = (int)(u32t)keyArr[r0 + t];
  __syncthreads();
  float lsum = 0.f;
  for (int rr = 0; rr < 128; ++rr) {
    const int row  = r0 + rr;
    const int code = codes[rr];
    const float q  = Etg[(size_t)code * DDIM + t];
    const float xv = x[(size_t)row * DDIM + t];
    out[(size_t)row * DDIM + t] = q;
    const float df = q - xv;
    lsum += df * df;
  }
  #pragma unroll
  for (int off = 32; off; off >>= 1) lsum += __shfl_xor(lsum, off);
  if ((t & 63) == 0) lpart[t >> 6] = lsum;
  __syncthreads();
  if (t == 0) partial[blockIdx.x] = (lpart[0] + lpart[1]) + (lpart[2] + lpart[3]);
}

// --- final deterministic loss reduction ---
__global__ __launch_bounds__(256) void vq_final(const float* __restrict__ partial,
                                                float* __restrict__ loss_out) {
  double s = 0.0;
  for (int i = threadIdx.x; i < 512; i += 256) s += (double)partial[i];
  #pragma unroll
  for (int off = 32; off; off >>= 1) s += __shfl_xor(s, off);
  __shared__ double sh[4];
  if ((threadIdx.x & 63) == 0) sh[threadIdx.x >> 6] = s;
  __syncthreads();
  if (threadIdx.x == 0) {
    const double mean = (sh[0] + sh[1] + sh[2] + sh[3]) / 16777216.0;
    loss_out[0] = (float)(0.25 * mean - mean);
  }
}

extern "C" void kernel_launch(void* const* d_in, const int* in_sizes, int n_in,
                              void* d_out, int out_size, void* d_ws, size_t ws_size,
                              hipStream_t stream) {
  const float* x = (const float*)d_in[0];   // [65536, 256]
  const float* E = (const float*)d_in[1];   // [256, 2048]
  float* out = (float*)d_out;
  char*  ws  = (char*)d_ws;

  // ws layout (bytes): keyArr 512K | enorm 8K | frow 256K | partial 2K | Etg 2M | Bp 3M  (~5.8 MB)
  u64t*  keyArr  = (u64t*)ws;
  float* enorm   = (float*)(ws + 524288);
  float* frow    = (float*)(ws + 524288 + 8192);
  float* partial = (float*)(ws + 524288 + 8192 + 262144);
  float* Etg     = (float*)(ws + 524288 + 8192 + 262144 + 2048);
  unsigned short* Bp = (unsigned short*)(ws + 524288 + 8192 + 262144 + 2048 + 2097152);

  unsigned short* Ap = (unsigned short*)d_out;   // A' overlay on out (consumed before gather writes)

  hipFuncSetAttribute(reinterpret_cast<const void*>(vq_nn),
                      hipFuncAttributeMaxDynamicSharedMemorySize, 131072);

  prep_A  <<<NROWS / 8, 256, 0, stream>>>(x, Ap, frow, keyArr);
  prep_B  <<<KCODE,     256, 0, stream>>>(E, Bp, enorm, Etg);
  vq_nn   <<<2048,      512, 131072, stream>>>(Ap, Bp, enorm, frow, keyArr);
  vq_gather<<<512,      256, 0, stream>>>(keyArr, Etg, x, out, partial);
  vq_final<<<1,         256, 0, stream>>>(partial, out + (size_t)NROWS * DDIM);
}

// Round 4
// 234.672 us; speedup vs baseline: 3.7912x; 1.0347x over previous
//
#include <hip/hip_runtime.h>

typedef __attribute__((ext_vector_type(8))) short bf16x8;
typedef __attribute__((ext_vector_type(4))) float f32x4;
typedef __attribute__((ext_vector_type(8))) unsigned short u16x8;
typedef unsigned long long u64t;
typedef unsigned int u32t;

#define NROWS 65536
#define DDIM  256
#define KCODE 2048

__device__ __forceinline__ unsigned short f2bf_rne(float f) {
  unsigned int u = __builtin_bit_cast(unsigned int, f);
  unsigned int r = (u + 0x7fffu + ((u >> 16) & 1u)) >> 16;
  return (unsigned short)r;
}
__device__ __forceinline__ float bf2f(unsigned short h) {
  unsigned int u = ((unsigned int)h) << 16;
  return __builtin_bit_cast(float, u);
}

typedef const unsigned int __attribute__((address_space(1)))* gp1_t;
typedef unsigned int __attribute__((address_space(3)))* lp3_t;
__device__ __forceinline__ void gload_lds16(const void* g, void* l) {
  __builtin_amdgcn_global_load_lds((gp1_t)g, (lp3_t)l, 16, 0, 0);
}

__device__ __forceinline__ u64t shfl_xor_u64(u64t v, int off) {
  u32t lo = (u32t)v, hi = (u32t)(v >> 32);
  lo = __shfl_xor(lo, off);
  hi = __shfl_xor(hi, off);
  return ((u64t)hi << 32) | lo;
}

// --- prep A: x -> [hi(256)|lo(256)] bf16 per row (overlay on d_out) + ||x||^2 + key init ---
__global__ __launch_bounds__(256) void prep_A(const float* __restrict__ x,
                                              unsigned short* __restrict__ Ap,
                                              float* __restrict__ frow,
                                              u64t* __restrict__ keyArr) {
  const int t   = threadIdx.x;
  const int row = blockIdx.x * 8 + (t >> 5);
  const int d0  = (t & 31) * 8;
  const float* xr = x + (size_t)row * DDIM + d0;
  float4 v0 = *reinterpret_cast<const float4*>(xr);
  float4 v1 = *reinterpret_cast<const float4*>(xr + 4);
  float vv[8] = {v0.x, v0.y, v0.z, v0.w, v1.x, v1.y, v1.z, v1.w};
  u16x8 hi, lo;
  float ss = 0.f;
  #pragma unroll
  for (int i = 0; i < 8; ++i) {
    ss += vv[i] * vv[i];
    unsigned short h = f2bf_rne(vv[i]);
    hi[i] = h;
    lo[i] = f2bf_rne(vv[i] - bf2f(h));
  }
  char* rowp = (char*)Ap + (size_t)row * 1024;
  *reinterpret_cast<u16x8*>(rowp + d0 * 2)       = hi;
  *reinterpret_cast<u16x8*>(rowp + 512 + d0 * 2) = lo;
  #pragma unroll
  for (int off = 16; off; off >>= 1) ss += __shfl_xor(ss, off);
  if ((t & 31) == 0) { frow[row] = ss; keyArr[row] = ~0ull; }
}

// --- prep B: E[d][k] -> Bp[k][768]=[hi|hi|lo] bf16 k-major; enorm; Etg[k][d] fp32 ---
__global__ __launch_bounds__(256) void prep_B(const float* __restrict__ E,
                                              unsigned short* __restrict__ Bp,
                                              float* __restrict__ enorm,
                                              float* __restrict__ Etg) {
  const int k0 = blockIdx.x;
  const int d  = threadIdx.x;
  float v = E[(size_t)d * KCODE + k0];
  Etg[(size_t)k0 * DDIM + d] = v;
  unsigned short h = f2bf_rne(v);
  unsigned short l = f2bf_rne(v - bf2f(h));
  unsigned short* col = Bp + (size_t)k0 * 768;
  col[d] = h; col[256 + d] = h; col[512 + d] = l;
  float s = v * v;
  #pragma unroll
  for (int off = 32; off; off >>= 1) s += __shfl_xor(s, off);
  __shared__ float wsum[4];
  if ((threadIdx.x & 63) == 0) wsum[threadIdx.x >> 6] = s;
  __syncthreads();
  if (threadIdx.x == 0) enorm[k0] = (wsum[0] + wsum[1]) + (wsum[2] + wsum[3]);
}

// --- main: transposed distance GEMM, m201-style 4-phase/K-tile schedule ---
__global__ __launch_bounds__(512, 2) void vq_nn(
    const unsigned short* __restrict__ Ap,   // x packed  [row][hi|lo]   1024 B/row
    const unsigned short* __restrict__ Bp,   // codes     [k][hi|hi|lo]  1536 B/code
    const float* __restrict__ enorm,
    const float* __restrict__ frow,
    u64t* __restrict__ keyArr)
{
  extern __shared__ __align__(16) char lds[];   // 2 x { codes 32K | x 32K } = 128 KB

  const int tid = threadIdx.x;
  const int w   = tid >> 6;
  const int l   = tid & 63;
  const int l15 = l & 15;
  const int lg  = l >> 4;
  const int wr  = w >> 2;      // code half (0..1)
  const int wc  = w & 3;       // x-col quarter (0..3)
  const int cb  = blockIdx.x >> 8;    // code block 0..7
  const int nb  = blockIdx.x & 255;   // x-row block 0..255

  const int rl0   = tid >> 3;
  const int chunk = (tid & 7) * 16;
  const int srcC  = chunk ^ ((rl0 & 7) << 4);   // pre-swizzled source byte (T2, both-sides)
  const char* BpB = (const char*)Bp + (size_t)cb * 256 * 1536;
  const char* ApB = (const char*)Ap + (size_t)nb * 256 * 1024;

  // quarter-stage q: 2 x global_load_lds (one code row-quarter + one x row-quarter)
  auto STAGE_Q = [&](int kb, char* buf, int q) {
    char* dstb = buf + w * 1024;
    const int xc = (kb < 8) ? kb : kb - 8;     // x virtual-K: [hi|lo|hi]
    gload_lds16(BpB + (size_t)(q * 64 + rl0) * 1536 + kb * 128 + srcC, dstb + q * 8192);
    gload_lds16(ApB + (size_t)(q * 64 + rl0) * 1024 + xc * 128 + srcC, dstb + 32768 + q * 8192);
  };

  const int swz = (l15 & 7) << 4;
  int aOff[8];
  #pragma unroll
  for (int fr = 0; fr < 8; ++fr) aOff[fr] = (wr * 128 + fr * 16 + l15) * 128;
  int bOff[4];
  #pragma unroll
  for (int fc = 0; fc < 4; ++fc) bOff[fc] = 32768 + (wc * 64 + fc * 16 + l15) * 128;

  f32x4 acc[8][4];
  #pragma unroll
  for (int fr = 0; fr < 8; ++fr)
    #pragma unroll
    for (int fc = 0; fc < 4; ++fc) acc[fr][fc] = (f32x4){0.f, 0.f, 0.f, 0.f};

  bf16x8 aF[4], bF[4];

#define READ_B(lb, ks)                                                        \
  _Pragma("unroll")                                                           \
  for (int fc = 0; fc < 4; ++fc)                                              \
    bF[fc] = *reinterpret_cast<const bf16x8*>((lb) + bOff[fc] + (((ks)*64 + lg*16) ^ swz));

#define READ_A(lb, ks, h)                                                     \
  _Pragma("unroll")                                                           \
  for (int i = 0; i < 4; ++i)                                                 \
    aF[i] = *reinterpret_cast<const bf16x8*>((lb) + aOff[(h)*4 + i] + (((ks)*64 + lg*16) ^ swz));

#define MFMA16(h)                                                             \
  __builtin_amdgcn_s_setprio(1);                                              \
  _Pragma("unroll")                                                           \
  for (int i = 0; i < 4; ++i)                                                 \
    _Pragma("unroll")                                                         \
    for (int fc = 0; fc < 4; ++fc)                                            \
      acc[(h)*4 + i][fc] =                                                    \
        __builtin_amdgcn_mfma_f32_16x16x32_bf16(aF[i], bF[fc], acc[(h)*4 + i][fc], 0, 0, 0); \
  __builtin_amdgcn_s_setprio(0);

  // prologue: full stage of K-tile 0 into buf0
  #pragma unroll
  for (int q = 0; q < 4; ++q) STAGE_Q(0, lds, q);

  for (int t = 0; t < 12; ++t) {
    const char* lb = lds + (t & 1) * 65536;
    char* sb = lds + ((t + 1) & 1) * 65536;
    const bool pref = (t < 11);

    // ---- phase 0: publish buf[t&1]; compute ks0 / code-half 0 ----
    if (pref) {
      STAGE_Q(t + 1, sb, 0);                              // 2 newest in flight
      asm volatile("s_waitcnt vmcnt(2)" ::: "memory");    // tile t's 8 loads drained
    } else {
      asm volatile("s_waitcnt vmcnt(0)" ::: "memory");    // epilogue drain (last tile)
    }
    __builtin_amdgcn_s_barrier();                         // all waves' loads landed
    READ_B(lb, 0); READ_A(lb, 0, 0);
    MFMA16(0);
    __builtin_amdgcn_s_barrier();

    // ---- phase 1: ks0 / half 1 ----
    READ_A(lb, 0, 1);
    if (pref) STAGE_Q(t + 1, sb, 1);
    __builtin_amdgcn_s_barrier();
    MFMA16(1);
    __builtin_amdgcn_s_barrier();

    // ---- phase 2: ks1 / half 0 ----
    READ_B(lb, 1); READ_A(lb, 1, 0);
    if (pref) STAGE_Q(t + 1, sb, 2);
    __builtin_amdgcn_s_barrier();
    MFMA16(0);
    __builtin_amdgcn_s_barrier();

    // ---- phase 3: ks1 / half 1 ----
    READ_A(lb, 1, 1);
    if (pref) STAGE_Q(t + 1, sb, 3);
    __builtin_amdgcn_s_barrier();
    MFMA16(1);
    __builtin_amdgcn_s_barrier();
  }

  // ---- epilogue: dist -> packed u64 key -> fold -> atomicMin per x-row ----
  // C layout: row(code_l) = wr*128 + fr*16 + lg*4 + rg ; col(x_l) = wc*64 + fc*16 + l15
  float fcol[4];
  #pragma unroll
  for (int fc = 0; fc < 4; ++fc)
    fcol[fc] = frow[nb * 256 + wc * 64 + fc * 16 + l15];

  u64t bk[4] = {~0ull, ~0ull, ~0ull, ~0ull};
  #pragma unroll
  for (int fr = 0; fr < 8; ++fr) {
    const int cbase = cb * 256 + wr * 128 + fr * 16 + lg * 4;
    float4 en4 = *reinterpret_cast<const float4*>(enorm + cbase);
    const float en[4] = {en4.x, en4.y, en4.z, en4.w};
    #pragma unroll
    for (int fc = 0; fc < 4; ++fc)
      #pragma unroll
      for (int rg = 0; rg < 4; ++rg) {
        const float dist = (fcol[fc] + en[rg]) - 2.0f * acc[fr][fc][rg];
        const u64t key = ((u64t)__builtin_bit_cast(u32t, dist) << 32) | (u32t)(cbase + rg);
        if (key < bk[fc]) bk[fc] = key;
      }
  }
  #pragma unroll
  for (int off = 16; off <= 32; off <<= 1)
    #pragma unroll
    for (int fc = 0; fc < 4; ++fc) {
      const u64t o = shfl_xor_u64(bk[fc], off);
      if (o < bk[fc]) bk[fc] = o;
    }
  if (lg == 0) {
    #pragma unroll
    for (int fc = 0; fc < 4; ++fc)
      atomicMin(&keyArr[nb * 256 + wc * 64 + fc * 16 + l15], bk[fc]);
  }
#undef READ_B
#undef READ_A
#undef MFMA16
}

// --- gather: key -> code -> out write + loss partial ---
__global__ __launch_bounds__(256) void vq_gather(const u64t* __restrict__ keyArr,
                                                 const float* __restrict__ Etg,
                                                 const float* __restrict__ x,
                                                 float* __restrict__ out,
                                                 float* __restrict__ partial) {
  __shared__ int codes[128];
  __shared__ float lpart[4];
  const int t  = threadIdx.x;
  const int r0 = blockIdx.x * 128;
  if (t < 128) codes[t] = (int)(u32t)keyArr[r0 + t];
  __syncthreads();
  float lsum = 0.f;
  for (int rr = 0; rr < 128; ++rr) {
    const int row  = r0 + rr;
    const int code = codes[rr];
    const float q  = Etg[(size_t)code * DDIM + t];
    const float xv = x[(size_t)row * DDIM + t];
    out[(size_t)row * DDIM + t] = q;
    const float df = q - xv;
    lsum += df * df;
  }
  #pragma unroll
  for (int off = 32; off; off >>= 1) lsum += __shfl_xor(lsum, off);
  if ((t & 63) == 0) lpart[t >> 6] = lsum;
  __syncthreads();
  if (t == 0) partial[blockIdx.x] = (lpart[0] + lpart[1]) + (lpart[2] + lpart[3]);
}

// --- final deterministic loss reduction ---
__global__ __launch_bounds__(256) void vq_final(const float* __restrict__ partial,
                                                float* __restrict__ loss_out) {
  double s = 0.0;
  for (int i = threadIdx.x; i < 512; i += 256) s += (double)partial[i];
  #pragma unroll
  for (int off = 32; off; off >>= 1) s += __shfl_xor(s, off);
  __shared__ double sh[4];
  if ((threadIdx.x & 63) == 0) sh[threadIdx.x >> 6] = s;
  __syncthreads();
  if (threadIdx.x == 0) {
    const double mean = (sh[0] + sh[1] + sh[2] + sh[3]) / 16777216.0;
    loss_out[0] = (float)(0.25 * mean - mean);
  }
}

extern "C" void kernel_launch(void* const* d_in, const int* in_sizes, int n_in,
                              void* d_out, int out_size, void* d_ws, size_t ws_size,
                              hipStream_t stream) {
  const float* x = (const float*)d_in[0];   // [65536, 256]
  const float* E = (const float*)d_in[1];   // [256, 2048]
  float* out = (float*)d_out;
  char*  ws  = (char*)d_ws;

  // ws layout (bytes): keyArr 512K | enorm 8K | frow 256K | partial 2K | Etg 2M | Bp 3M  (~5.8 MB)
  u64t*  keyArr  = (u64t*)ws;
  float* enorm   = (float*)(ws + 524288);
  float* frow    = (float*)(ws + 524288 + 8192);
  float* partial = (float*)(ws + 524288 + 8192 + 262144);
  float* Etg     = (float*)(ws + 524288 + 8192 + 262144 + 2048);
  unsigned short* Bp = (unsigned short*)(ws + 524288 + 8192 + 262144 + 2048 + 2097152);

  unsigned short* Ap = (unsigned short*)d_out;   // A' overlay on out (consumed before gather writes)

  hipFuncSetAttribute(reinterpret_cast<const void*>(vq_nn),
                      hipFuncAttributeMaxDynamicSharedMemorySize, 131072);

  prep_A  <<<NROWS / 8, 256, 0, stream>>>(x, Ap, frow, keyArr);
  prep_B  <<<KCODE,     256, 0, stream>>>(E, Bp, enorm, Etg);
  vq_nn   <<<2048,      512, 131072, stream>>>(Ap, Bp, enorm, frow, keyArr);
  vq_gather<<<512,      256, 0, stream>>>(keyArr, Etg, x, out, partial);
  vq_final<<<1,         256, 0, stream>>>(partial, out + (size_t)NROWS * DDIM);
}

// Round 6
// 228.377 us; speedup vs baseline: 3.8957x; 1.0276x over previous
//
#include <hip/hip_runtime.h>

typedef __attribute__((ext_vector_type(8))) short bf16x8;
typedef __attribute__((ext_vector_type(4))) float f32x4;
typedef __attribute__((ext_vector_type(8))) unsigned short u16x8;
typedef unsigned long long u64t;
typedef unsigned int u32t;

#define NROWS 65536
#define DDIM  256
#define KCODE 2048

__device__ __forceinline__ unsigned short f2bf_rne(float f) {
  unsigned int u = __builtin_bit_cast(unsigned int, f);
  unsigned int r = (u + 0x7fffu + ((u >> 16) & 1u)) >> 16;
  return (unsigned short)r;
}
__device__ __forceinline__ float bf2f(unsigned short h) {
  unsigned int u = ((unsigned int)h) << 16;
  return __builtin_bit_cast(float, u);
}

typedef const unsigned int __attribute__((address_space(1)))* gp1_t;
typedef unsigned int __attribute__((address_space(3)))* lp3_t;
__device__ __forceinline__ void gload_lds16(const void* g, void* l) {
  __builtin_amdgcn_global_load_lds((gp1_t)g, (lp3_t)l, 16, 0, 0);
}

__device__ __forceinline__ u64t shfl_xor_u64(u64t v, int off) {
  u32t lo = (u32t)v, hi = (u32t)(v >> 32);
  lo = __shfl_xor(lo, off);
  hi = __shfl_xor(hi, off);
  return ((u64t)hi << 32) | lo;
}

// --- prep A: x -> [hi(256)|lo(256)] bf16 per row (overlay on d_out) + ||x||^2 + key init ---
__global__ __launch_bounds__(256) void prep_A(const float* __restrict__ x,
                                              unsigned short* __restrict__ Ap,
                                              float* __restrict__ frow,
                                              u64t* __restrict__ keyArr) {
  const int t   = threadIdx.x;
  const int row = blockIdx.x * 8 + (t >> 5);
  const int d0  = (t & 31) * 8;
  const float* xr = x + (size_t)row * DDIM + d0;
  float4 v0 = *reinterpret_cast<const float4*>(xr);
  float4 v1 = *reinterpret_cast<const float4*>(xr + 4);
  float vv[8] = {v0.x, v0.y, v0.z, v0.w, v1.x, v1.y, v1.z, v1.w};
  u16x8 hi, lo;
  float ss = 0.f;
  #pragma unroll
  for (int i = 0; i < 8; ++i) {
    ss += vv[i] * vv[i];
    unsigned short h = f2bf_rne(vv[i]);
    hi[i] = h;
    lo[i] = f2bf_rne(vv[i] - bf2f(h));
  }
  char* rowp = (char*)Ap + (size_t)row * 1024;
  *reinterpret_cast<u16x8*>(rowp + d0 * 2)       = hi;
  *reinterpret_cast<u16x8*>(rowp + 512 + d0 * 2) = lo;
  #pragma unroll
  for (int off = 16; off; off >>= 1) ss += __shfl_xor(ss, off);
  if ((t & 31) == 0) { frow[row] = ss; keyArr[row] = ~0ull; }
}

// --- prep B: E[d][k] -> Bp[k][768]=[hi|hi|lo] bf16 k-major; enorm; Etg[k][d] fp32 ---
__global__ __launch_bounds__(256) void prep_B(const float* __restrict__ E,
                                              unsigned short* __restrict__ Bp,
                                              float* __restrict__ enorm,
                                              float* __restrict__ Etg) {
  const int k0 = blockIdx.x;
  const int d  = threadIdx.x;
  float v = E[(size_t)d * KCODE + k0];
  Etg[(size_t)k0 * DDIM + d] = v;
  unsigned short h = f2bf_rne(v);
  unsigned short l = f2bf_rne(v - bf2f(h));
  unsigned short* col = Bp + (size_t)k0 * 768;
  col[d] = h; col[256 + d] = h; col[512 + d] = l;
  float s = v * v;
  #pragma unroll
  for (int off = 32; off; off >>= 1) s += __shfl_xor(s, off);
  __shared__ float wsum[4];
  if ((threadIdx.x & 63) == 0) wsum[threadIdx.x >> 6] = s;
  __syncthreads();
  if (threadIdx.x == 0) enorm[k0] = (wsum[0] + wsum[1]) + (wsum[2] + wsum[3]);
}

// --- main: transposed distance GEMM; corrected derived per-phase waits ---
// Consumption per tile: P0 needs ALL x quarters (waves read x quarter wc) +
// codes q0,q2; P1 needs codes q1,q3; P2/P3 reuse published rows (ks=1).
// Issue order for t+1 therefore: P0: x q0,q1 | P1: x q2,q3 | P2: codes q0,q2
// | P3: codes q1,q3. Waits: P0 vmcnt(4) -> forces all x + codes q0,q2;
// P1 vmcnt(4) -> forces codes q1,q3; P2/P3 no wait.
__global__ __launch_bounds__(512, 2) void vq_nn(
    const unsigned short* __restrict__ Ap,   // x packed  [row][hi|lo]   1024 B/row
    const unsigned short* __restrict__ Bp,   // codes     [k][hi|hi|lo]  1536 B/code
    const float* __restrict__ enorm,
    const float* __restrict__ frow,
    u64t* __restrict__ keyArr)
{
  extern __shared__ __align__(16) char lds[];   // 2 x { codes 32K | x 32K } = 128 KB

  const int tid = threadIdx.x;
  const int w   = tid >> 6;
  const int l   = tid & 63;
  const int l15 = l & 15;
  const int lg  = l >> 4;
  const int wr  = w >> 2;      // code half (0..1)
  const int wc  = w & 3;       // x-col quarter (0..3)
  const int cb  = blockIdx.x >> 8;    // code block 0..7
  const int nb  = blockIdx.x & 255;   // x-row block 0..255

  const int rl0   = tid >> 3;
  const int chunk = (tid & 7) * 16;
  const int srcC  = chunk ^ ((rl0 & 7) << 4);   // pre-swizzled source byte (T2, both-sides)
  const char* BpB = (const char*)Bp + (size_t)cb * 256 * 1536;
  const char* ApB = (const char*)Ap + (size_t)nb * 256 * 1024;

  // fcol preload FIRST: oldest vmem ops, drained by the first vmcnt(4)
  float fcol[4];
  #pragma unroll
  for (int fc = 0; fc < 4; ++fc)
    fcol[fc] = frow[nb * 256 + wc * 64 + fc * 16 + l15];

  auto STAGE_C = [&](int kb, char* buf, int q) {   // one CODES row-quarter (64 rows x 128B)
    gload_lds16(BpB + (size_t)(q * 64 + rl0) * 1536 + kb * 128 + srcC,
                buf + w * 1024 + q * 8192);
  };
  auto STAGE_X = [&](int kb, char* buf, int q) {   // one X row-quarter
    const int xc = (kb < 8) ? kb : kb - 8;         // x virtual-K: [hi|lo|hi]
    gload_lds16(ApB + (size_t)(q * 64 + rl0) * 1024 + xc * 128 + srcC,
                buf + w * 1024 + 32768 + q * 8192);
  };

  const int swz = (l15 & 7) << 4;
  int aOff[8];
  #pragma unroll
  for (int fr = 0; fr < 8; ++fr) aOff[fr] = (wr * 128 + fr * 16 + l15) * 128;   // codes
  int bOff[4];
  #pragma unroll
  for (int fc = 0; fc < 4; ++fc) bOff[fc] = 32768 + (wc * 64 + fc * 16 + l15) * 128;  // x

  f32x4 acc[8][4];
  #pragma unroll
  for (int fr = 0; fr < 8; ++fr)
    #pragma unroll
    for (int fc = 0; fc < 4; ++fc) acc[fr][fc] = (f32x4){0.f, 0.f, 0.f, 0.f};

  bf16x8 aF[4], bF[4];

#define READ_B(lb, ks)                                                        \
  _Pragma("unroll")                                                           \
  for (int fc = 0; fc < 4; ++fc)                                              \
    bF[fc] = *reinterpret_cast<const bf16x8*>((lb) + bOff[fc] + (((ks)*64 + lg*16) ^ swz));

#define READ_A(lb, ks, h)                                                     \
  _Pragma("unroll")                                                           \
  for (int i = 0; i < 4; ++i)                                                 \
    aF[i] = *reinterpret_cast<const bf16x8*>((lb) + aOff[(h)*4 + i] + (((ks)*64 + lg*16) ^ swz));

#define MFMA16(h)                                                             \
  __builtin_amdgcn_s_setprio(1);                                              \
  _Pragma("unroll")                                                           \
  for (int i = 0; i < 4; ++i)                                                 \
    _Pragma("unroll")                                                         \
    for (int fc = 0; fc < 4; ++fc)                                            \
      acc[(h)*4 + i][fc] =                                                    \
        __builtin_amdgcn_mfma_f32_16x16x32_bf16(aF[i], bF[fc], acc[(h)*4 + i][fc], 0, 0, 0); \
  __builtin_amdgcn_s_setprio(0);

  // prologue: tile 0 in issue order x q0..q3, codes q0,q2,q1,q3
  STAGE_X(0, lds, 0); STAGE_X(0, lds, 1); STAGE_X(0, lds, 2); STAGE_X(0, lds, 3);
  STAGE_C(0, lds, 0); STAGE_C(0, lds, 2); STAGE_C(0, lds, 1); STAGE_C(0, lds, 3);

  for (int t = 0; t < 12; ++t) {
    const char* lb = lds + (t & 1) * 65536;
    char* sb = lds + ((t + 1) & 1) * 65536;
    const bool pref = (t < 11);

    // ---- P0: needs ALL x(t) + codes(t) q0,q2 ----
    if (pref) {
      STAGE_X(t + 1, sb, 0); STAGE_X(t + 1, sb, 1);
      asm volatile("s_waitcnt vmcnt(4)" ::: "memory");   // leaves t.cq1,t.cq3 + 2 new x
    } else {
      asm volatile("s_waitcnt vmcnt(2)" ::: "memory");   // leaves t.cq1,t.cq3
    }
    __builtin_amdgcn_s_barrier();                        // publish x-all + codes q0,q2
    READ_B(lb, 0); READ_A(lb, 0, 0);
    MFMA16(0);

    // ---- P1: needs codes(t) q1,q3 ----
    if (pref) {
      STAGE_X(t + 1, sb, 2); STAGE_X(t + 1, sb, 3);
      asm volatile("s_waitcnt vmcnt(4)" ::: "memory");   // leaves 4 new t+1 x's
    } else {
      asm volatile("s_waitcnt vmcnt(0)" ::: "memory");
    }
    __builtin_amdgcn_s_barrier();                        // publish codes q1,q3
    READ_A(lb, 0, 1);
    MFMA16(1);

    // ---- P2: ks1 of already-published rows; no wait ----
    if (pref) { STAGE_C(t + 1, sb, 0); STAGE_C(t + 1, sb, 2); }
    READ_B(lb, 1); READ_A(lb, 1, 0);
    MFMA16(0);

    // ---- P3: ks1 / codes-half 1; no wait ----
    if (pref) { STAGE_C(t + 1, sb, 1); STAGE_C(t + 1, sb, 3); }
    READ_A(lb, 1, 1);
    MFMA16(1);
    __builtin_amdgcn_sched_barrier(0);                   // pin reads+MFMA before fence
    asm volatile("s_waitcnt lgkmcnt(0)" ::: "memory");   // wave's LDS reads complete
    __builtin_amdgcn_s_barrier();                        // fence before sb'=lb overwrite
  }

  // ---- epilogue: dist -> packed u64 key -> fold -> atomicMin per x-row ----
  // C layout: row(code_l) = wr*128 + fr*16 + lg*4 + rg ; col(x_l) = wc*64 + fc*16 + l15
  u64t bk[4] = {~0ull, ~0ull, ~0ull, ~0ull};
  #pragma unroll
  for (int fr = 0; fr < 8; ++fr) {
    const int cbase = cb * 256 + wr * 128 + fr * 16 + lg * 4;
    float4 en4 = *reinterpret_cast<const float4*>(enorm + cbase);
    const float en[4] = {en4.x, en4.y, en4.z, en4.w};
    #pragma unroll
    for (int fc = 0; fc < 4; ++fc)
      #pragma unroll
      for (int rg = 0; rg < 4; ++rg) {
        const float dist = (fcol[fc] + en[rg]) - 2.0f * acc[fr][fc][rg];
        const u64t key = ((u64t)__builtin_bit_cast(u32t, dist) << 32) | (u32t)(cbase + rg);
        if (key < bk[fc]) bk[fc] = key;
      }
  }
  #pragma unroll
  for (int off = 16; off <= 32; off <<= 1)
    #pragma unroll
    for (int fc = 0; fc < 4; ++fc) {
      const u64t o = shfl_xor_u64(bk[fc], off);
      if (o < bk[fc]) bk[fc] = o;
    }
  if (lg == 0) {
    #pragma unroll
    for (int fc = 0; fc < 4; ++fc)
      atomicMin(&keyArr[nb * 256 + wc * 64 + fc * 16 + l15], bk[fc]);
  }
#undef READ_B
#undef READ_A
#undef MFMA16
}

// --- gather: key -> code -> out write + loss partial ---
__global__ __launch_bounds__(256) void vq_gather(const u64t* __restrict__ keyArr,
                                                 const float* __restrict__ Etg,
                                                 const float* __restrict__ x,
                                                 float* __restrict__ out,
                                                 float* __restrict__ partial) {
  __shared__ int codes[128];
  __shared__ float lpart[4];
  const int t  = threadIdx.x;
  const int r0 = blockIdx.x * 128;
  if (t < 128) codes[t] = (int)(u32t)keyArr[r0 + t];
  __syncthreads();
  float lsum = 0.f;
  for (int rr = 0; rr < 128; ++rr) {
    const int row  = r0 + rr;
    const int code = codes[rr];
    const float q  = Etg[(size_t)code * DDIM + t];
    const float xv = x[(size_t)row * DDIM + t];
    out[(size_t)row * DDIM + t] = q;
    const float df = q - xv;
    lsum += df * df;
  }
  #pragma unroll
  for (int off = 32; off; off >>= 1) lsum += __shfl_xor(lsum, off);
  if ((t & 63) == 0) lpart[t >> 6] = lsum;
  __syncthreads();
  if (t == 0) partial[blockIdx.x] = (lpart[0] + lpart[1]) + (lpart[2] + lpart[3]);
}

// --- final deterministic loss reduction ---
__global__ __launch_bounds__(256) void vq_final(const float* __restrict__ partial,
                                                float* __restrict__ loss_out) {
  double s = 0.0;
  for (int i = threadIdx.x; i < 512; i += 256) s += (double)partial[i];
  #pragma unroll
  for (int off = 32; off; off >>= 1) s += __shfl_xor(s, off);
  __shared__ double sh[4];
  if ((threadIdx.x & 63) == 0) sh[threadIdx.x >> 6] = s;
  __syncthreads();
  if (threadIdx.x == 0) {
    const double mean = (sh[0] + sh[1] + sh[2] + sh[3]) / 16777216.0;
    loss_out[0] = (float)(0.25 * mean - mean);
  }
}

extern "C" void kernel_launch(void* const* d_in, const int* in_sizes, int n_in,
                              void* d_out, int out_size, void* d_ws, size_t ws_size,
                              hipStream_t stream) {
  const float* x = (const float*)d_in[0];   // [65536, 256]
  const float* E = (const float*)d_in[1];   // [256, 2048]
  float* out = (float*)d_out;
  char*  ws  = (char*)d_ws;

  // ws layout (bytes): keyArr 512K | enorm 8K | frow 256K | partial 2K | Etg 2M | Bp 3M  (~5.8 MB)
  u64t*  keyArr  = (u64t*)ws;
  float* enorm   = (float*)(ws + 524288);
  float* frow    = (float*)(ws + 524288 + 8192);
  float* partial = (float*)(ws + 524288 + 8192 + 262144);
  float* Etg     = (float*)(ws + 524288 + 8192 + 262144 + 2048);
  unsigned short* Bp = (unsigned short*)(ws + 524288 + 8192 + 262144 + 2048 + 2097152);

  unsigned short* Ap = (unsigned short*)d_out;   // A' overlay on out (consumed before gather writes)

  hipFuncSetAttribute(reinterpret_cast<const void*>(vq_nn),
                      hipFuncAttributeMaxDynamicSharedMemorySize, 131072);

  prep_A  <<<NROWS / 8, 256, 0, stream>>>(x, Ap, frow, keyArr);
  prep_B  <<<KCODE,     256, 0, stream>>>(E, Bp, enorm, Etg);
  vq_nn   <<<2048,      512, 131072, stream>>>(Ap, Bp, enorm, frow, keyArr);
  vq_gather<<<512,      256, 0, stream>>>(keyArr, Etg, x, out, partial);
  vq_final<<<1,         256, 0, stream>>>(partial, out + (size_t)NROWS * DDIM);
}

// Round 7
// 227.643 us; speedup vs baseline: 3.9083x; 1.0032x over previous
//
#include <hip/hip_runtime.h>

typedef __attribute__((ext_vector_type(8))) short bf16x8;
typedef __attribute__((ext_vector_type(4))) float f32x4;
typedef __attribute__((ext_vector_type(8))) unsigned short u16x8;
typedef unsigned long long u64t;
typedef unsigned int u32t;

#define NROWS 65536
#define DDIM  256
#define KCODE 2048

__device__ __forceinline__ unsigned short f2bf_rne(float f) {
  unsigned int u = __builtin_bit_cast(unsigned int, f);
  unsigned int r = (u + 0x7fffu + ((u >> 16) & 1u)) >> 16;
  return (unsigned short)r;
}
__device__ __forceinline__ float bf2f(unsigned short h) {
  unsigned int u = ((unsigned int)h) << 16;
  return __builtin_bit_cast(float, u);
}

typedef const unsigned int __attribute__((address_space(1)))* gp1_t;
typedef unsigned int __attribute__((address_space(3)))* lp3_t;
__device__ __forceinline__ void gload_lds16(const void* g, void* l) {
  __builtin_amdgcn_global_load_lds((gp1_t)g, (lp3_t)l, 16, 0, 0);
}

__device__ __forceinline__ u64t shfl_xor_u64(u64t v, int off) {
  u32t lo = (u32t)v, hi = (u32t)(v >> 32);
  lo = __shfl_xor(lo, off);
  hi = __shfl_xor(hi, off);
  return ((u64t)hi << 32) | lo;
}

// --- prep A: x -> [hi(256)|lo(256)] bf16 per row (overlay on d_out) + ||x||^2 + key init ---
__global__ __launch_bounds__(256) void prep_A(const float* __restrict__ x,
                                              unsigned short* __restrict__ Ap,
                                              float* __restrict__ frow,
                                              u64t* __restrict__ keyArr) {
  const int t   = threadIdx.x;
  const int row = blockIdx.x * 8 + (t >> 5);
  const int d0  = (t & 31) * 8;
  const float* xr = x + (size_t)row * DDIM + d0;
  float4 v0 = *reinterpret_cast<const float4*>(xr);
  float4 v1 = *reinterpret_cast<const float4*>(xr + 4);
  float vv[8] = {v0.x, v0.y, v0.z, v0.w, v1.x, v1.y, v1.z, v1.w};
  u16x8 hi, lo;
  float ss = 0.f;
  #pragma unroll
  for (int i = 0; i < 8; ++i) {
    ss += vv[i] * vv[i];
    unsigned short h = f2bf_rne(vv[i]);
    hi[i] = h;
    lo[i] = f2bf_rne(vv[i] - bf2f(h));
  }
  char* rowp = (char*)Ap + (size_t)row * 1024;
  *reinterpret_cast<u16x8*>(rowp + d0 * 2)       = hi;
  *reinterpret_cast<u16x8*>(rowp + 512 + d0 * 2) = lo;
  #pragma unroll
  for (int off = 16; off; off >>= 1) ss += __shfl_xor(ss, off);
  if ((t & 31) == 0) { frow[row] = ss; keyArr[row] = ~0ull; }
}

// --- prep B: E[d][k] -> Bp[k][768]=[hi|hi|lo] bf16 k-major; enorm; Etg[k][d] fp32 ---
__global__ __launch_bounds__(256) void prep_B(const float* __restrict__ E,
                                              unsigned short* __restrict__ Bp,
                                              float* __restrict__ enorm,
                                              float* __restrict__ Etg) {
  const int k0 = blockIdx.x;
  const int d  = threadIdx.x;
  float v = E[(size_t)d * KCODE + k0];
  Etg[(size_t)k0 * DDIM + d] = v;
  unsigned short h = f2bf_rne(v);
  unsigned short l = f2bf_rne(v - bf2f(h));
  unsigned short* col = Bp + (size_t)k0 * 768;
  col[d] = h; col[256 + d] = h; col[512 + d] = l;
  float s = v * v;
  #pragma unroll
  for (int off = 32; off; off >>= 1) s += __shfl_xor(s, off);
  __shared__ float wsum[4];
  if ((threadIdx.x & 63) == 0) wsum[threadIdx.x >> 6] = s;
  __syncthreads();
  if (threadIdx.x == 0) enorm[k0] = (wsum[0] + wsum[1]) + (wsum[2] + wsum[3]);
}

// --- main: transposed distance GEMM; full-tile prefetch, ONE barrier per tile ---
// Sync design: tile t's 8 stage-loads are the FIRST ops of tile t-1... no:
// issued first thing in tile t-1's body for t (full-tile lookahead ~2500cy).
// Single sync point per tile: vmcnt(0)+lgkmcnt(0)+s_barrier at tile end,
// which (a) publishes tile t+1's staged data, (b) guarantees all waves'
// LDS reads of the buffer about to be overwritten have retired.
__global__ __launch_bounds__(512, 2) void vq_nn(
    const unsigned short* __restrict__ Ap,   // x packed  [row][hi|lo]   1024 B/row
    const unsigned short* __restrict__ Bp,   // codes     [k][hi|hi|lo]  1536 B/code
    const float* __restrict__ enorm,
    const float* __restrict__ frow,
    u64t* __restrict__ keyArr)
{
  extern __shared__ __align__(16) char lds[];   // 2 x { codes 32K | x 32K } = 128 KB

  const int tid = threadIdx.x;
  const int w   = tid >> 6;
  const int l   = tid & 63;
  const int l15 = l & 15;
  const int lg  = l >> 4;
  const int wr  = w >> 2;      // code half (0..1)
  const int wc  = w & 3;       // x-col quarter (0..3)

  // XCD-aware swizzle: each XCD gets a contiguous nb-range x all code blocks
  // -> per-XCD L2 working set = 4 x-slabs (1MB) + all codes (3MB) ~ 4MB L2.
  const int xcd = blockIdx.x & 7;
  const int seq = blockIdx.x >> 3;
  const int cb  = seq & 7;                  // code block 0..7
  const int nb  = xcd * 32 + (seq >> 3);    // x-row block 0..255

  const int rl0   = tid >> 3;
  const int chunk = (tid & 7) * 16;
  const int srcC  = chunk ^ ((rl0 & 7) << 4);   // pre-swizzled source byte (T2, both-sides)
  const char* BpB = (const char*)Bp + (size_t)cb * 256 * 1536;
  const char* ApB = (const char*)Ap + (size_t)nb * 256 * 1024;

  // fcol preload FIRST: drained by the prologue vmcnt(0)
  float fcol[4];
  #pragma unroll
  for (int fc = 0; fc < 4; ++fc)
    fcol[fc] = frow[nb * 256 + wc * 64 + fc * 16 + l15];

  auto STAGE_ALL = [&](int kb, char* buf) {      // full K-tile: 8 gload_lds
    char* dstb = buf + w * 1024;
    const int xc = (kb < 8) ? kb : kb - 8;       // x virtual-K: [hi|lo|hi]
    #pragma unroll
    for (int q = 0; q < 4; ++q)                  // x: 256 rows x 128 B
      gload_lds16(ApB + (size_t)(q * 64 + rl0) * 1024 + xc * 128 + srcC,
                  dstb + 32768 + q * 8192);
    #pragma unroll
    for (int q = 0; q < 4; ++q)                  // codes: 256 rows x 128 B
      gload_lds16(BpB + (size_t)(q * 64 + rl0) * 1536 + kb * 128 + srcC,
                  dstb + q * 8192);
  };

  const int swz = (l15 & 7) << 4;
  int aOff[8];
  #pragma unroll
  for (int fr = 0; fr < 8; ++fr) aOff[fr] = (wr * 128 + fr * 16 + l15) * 128;   // codes
  int bOff[4];
  #pragma unroll
  for (int fc = 0; fc < 4; ++fc) bOff[fc] = 32768 + (wc * 64 + fc * 16 + l15) * 128;  // x

  f32x4 acc[8][4];
  #pragma unroll
  for (int fr = 0; fr < 8; ++fr)
    #pragma unroll
    for (int fc = 0; fc < 4; ++fc) acc[fr][fc] = (f32x4){0.f, 0.f, 0.f, 0.f};

  bf16x8 a0[4], a1[4], b0[4], b1[4];

#define READ_Bv(dst, lb, ks)                                                  \
  _Pragma("unroll")                                                           \
  for (int fc = 0; fc < 4; ++fc)                                              \
    dst[fc] = *reinterpret_cast<const bf16x8*>((lb) + bOff[fc] + (((ks)*64 + lg*16) ^ swz));

#define READ_Av(dst, lb, ks, h)                                               \
  _Pragma("unroll")                                                           \
  for (int i = 0; i < 4; ++i)                                                 \
    dst[i] = *reinterpret_cast<const bf16x8*>((lb) + aOff[(h)*4 + i] + (((ks)*64 + lg*16) ^ swz));

#define MFMA16v(h, av, bv)                                                    \
  __builtin_amdgcn_s_setprio(1);                                              \
  _Pragma("unroll")                                                           \
  for (int i = 0; i < 4; ++i)                                                 \
    _Pragma("unroll")                                                         \
    for (int fc = 0; fc < 4; ++fc)                                            \
      acc[(h)*4 + i][fc] =                                                    \
        __builtin_amdgcn_mfma_f32_16x16x32_bf16(av[i], bv[fc], acc[(h)*4 + i][fc], 0, 0, 0); \
  __builtin_amdgcn_s_setprio(0);

  // prologue: stage tile 0, publish
  STAGE_ALL(0, lds);
  asm volatile("s_waitcnt vmcnt(0)" ::: "memory");
  __builtin_amdgcn_s_barrier();

  for (int t = 0; t < 12; ++t) {
    const char* lb = lds + (t & 1) * 65536;
    char* sb = lds + ((t + 1) & 1) * 65536;

    if (t < 11) STAGE_ALL(t + 1, sb);     // full next tile in flight immediately

    // barrier-free tile body: compiler pipelines lgkmcnt between reads & MFMA
    READ_Bv(b0, lb, 0); READ_Av(a0, lb, 0, 0);
    READ_Av(a1, lb, 0, 1);
    READ_Bv(b1, lb, 1);
    MFMA16v(0, a0, b0);
    MFMA16v(1, a1, b0);
    READ_Av(a0, lb, 1, 0);
    READ_Av(a1, lb, 1, 1);
    MFMA16v(0, a0, b1);
    MFMA16v(1, a1, b1);

    if (t < 11) {
      __builtin_amdgcn_sched_barrier(0);    // pin reads+MFMA before the fence
      asm volatile("s_waitcnt vmcnt(0) lgkmcnt(0)" ::: "memory");  // publish t+1 (expected satisfied)
      __builtin_amdgcn_s_barrier();         // single sync point per tile
    }
  }

  // ---- epilogue: dist -> packed u64 key -> fold -> atomicMin per x-row ----
  // C layout: row(code_l) = wr*128 + fr*16 + lg*4 + rg ; col(x_l) = wc*64 + fc*16 + l15
  u64t bk[4] = {~0ull, ~0ull, ~0ull, ~0ull};
  #pragma unroll
  for (int fr = 0; fr < 8; ++fr) {
    const int cbase = cb * 256 + wr * 128 + fr * 16 + lg * 4;
    float4 en4 = *reinterpret_cast<const float4*>(enorm + cbase);
    const float en[4] = {en4.x, en4.y, en4.z, en4.w};
    #pragma unroll
    for (int fc = 0; fc < 4; ++fc)
      #pragma unroll
      for (int rg = 0; rg < 4; ++rg) {
        const float dist = (fcol[fc] + en[rg]) - 2.0f * acc[fr][fc][rg];
        const u64t key = ((u64t)__builtin_bit_cast(u32t, dist) << 32) | (u32t)(cbase + rg);
        if (key < bk[fc]) bk[fc] = key;
      }
  }
  #pragma unroll
  for (int off = 16; off <= 32; off <<= 1)
    #pragma unroll
    for (int fc = 0; fc < 4; ++fc) {
      const u64t o = shfl_xor_u64(bk[fc], off);
      if (o < bk[fc]) bk[fc] = o;
    }
  if (lg == 0) {
    #pragma unroll
    for (int fc = 0; fc < 4; ++fc)
      atomicMin(&keyArr[nb * 256 + wc * 64 + fc * 16 + l15], bk[fc]);
  }
#undef READ_Bv
#undef READ_Av
#undef MFMA16v
}

// --- gather: key -> code -> out write + loss partial ---
__global__ __launch_bounds__(256) void vq_gather(const u64t* __restrict__ keyArr,
                                                 const float* __restrict__ Etg,
                                                 const float* __restrict__ x,
                                                 float* __restrict__ out,
                                                 float* __restrict__ partial) {
  __shared__ int codes[128];
  __shared__ float lpart[4];
  const int t  = threadIdx.x;
  const int r0 = blockIdx.x * 128;
  if (t < 128) codes[t] = (int)(u32t)keyArr[r0 + t];
  __syncthreads();
  float lsum = 0.f;
  for (int rr = 0; rr < 128; ++rr) {
    const int row  = r0 + rr;
    const int code = codes[rr];
    const float q  = Etg[(size_t)code * DDIM + t];
    const float xv = x[(size_t)row * DDIM + t];
    out[(size_t)row * DDIM + t] = q;
    const float df = q - xv;
    lsum += df * df;
  }
  #pragma unroll
  for (int off = 32; off; off >>= 1) lsum += __shfl_xor(lsum, off);
  if ((t & 63) == 0) lpart[t >> 6] = lsum;
  __syncthreads();
  if (t == 0) partial[blockIdx.x] = (lpart[0] + lpart[1]) + (lpart[2] + lpart[3]);
}

// --- final deterministic loss reduction ---
__global__ __launch_bounds__(256) void vq_final(const float* __restrict__ partial,
                                                float* __restrict__ loss_out) {
  double s = 0.0;
  for (int i = threadIdx.x; i < 512; i += 256) s += (double)partial[i];
  #pragma unroll
  for (int off = 32; off; off >>= 1) s += __shfl_xor(s, off);
  __shared__ double sh[4];
  if ((threadIdx.x & 63) == 0) sh[threadIdx.x >> 6] = s;
  __syncthreads();
  if (threadIdx.x == 0) {
    const double mean = (sh[0] + sh[1] + sh[2] + sh[3]) / 16777216.0;
    loss_out[0] = (float)(0.25 * mean - mean);
  }
}

extern "C" void kernel_launch(void* const* d_in, const int* in_sizes, int n_in,
                              void* d_out, int out_size, void* d_ws, size_t ws_size,
                              hipStream_t stream) {
  const float* x = (const float*)d_in[0];   // [65536, 256]
  const float* E = (const float*)d_in[1];   // [256, 2048]
  float* out = (float*)d_out;
  char*  ws  = (char*)d_ws;

  // ws layout (bytes): keyArr 512K | enorm 8K | frow 256K | partial 2K | Etg 2M | Bp 3M  (~5.8 MB)
  u64t*  keyArr  = (u64t*)ws;
  float* enorm   = (float*)(ws + 524288);
  float* frow    = (float*)(ws + 524288 + 8192);
  float* partial = (float*)(ws + 524288 + 8192 + 262144);
  float* Etg     = (float*)(ws + 524288 + 8192 + 262144 + 2048);
  unsigned short* Bp = (unsigned short*)(ws + 524288 + 8192 + 262144 + 2048 + 2097152);

  unsigned short* Ap = (unsigned short*)d_out;   // A' overlay on out (consumed before gather writes)

  hipFuncSetAttribute(reinterpret_cast<const void*>(vq_nn),
                      hipFuncAttributeMaxDynamicSharedMemorySize, 131072);

  prep_A  <<<NROWS / 8, 256, 0, stream>>>(x, Ap, frow, keyArr);
  prep_B  <<<KCODE,     256, 0, stream>>>(E, Bp, enorm, Etg);
  vq_nn   <<<2048,      512, 131072, stream>>>(Ap, Bp, enorm, frow, keyArr);
  vq_gather<<<512,      256, 0, stream>>>(keyArr, Etg, x, out, partial);
  vq_final<<<1,         256, 0, stream>>>(partial, out + (size_t)NROWS * DDIM);
}